// Round 4
// baseline (145.743 us; speedup 1.0000x reference)
//
#include <hip/hip_runtime.h>
#include <math.h>

#define E 4
#define TPB 256
#define RPB 8
#define NWAVES (TPB / 64)
#define SINKHORN_ITERS 20
#define SINKHORN_EPS 1e-6f

typedef float f4 __attribute__((ext_vector_type(4)));

// ws layout: [0, E*D)        ws_pre    = softmax(H_pre)            (E x D)
//            [E*D, 2*E*D)    ws_post2  = H_res @ softmax(H_post)   (E x D)
//            [2*E*D, +32)    ws_small: hres[16], mx[8], sm[8]

// ---------------------------------------------------------------------------
// prep_stats: 1 block. Sinkhorn on wave 0 (lanes 0-15, shfl butterflies);
// each wave computes softmax stats (max, sumexp) for 2 of the 8 (mat,row)
// pairs with f4 loads + 6-step butterfly. No __syncthreads at all.
// ---------------------------------------------------------------------------
__global__ __launch_bounds__(TPB) void prep_stats(
    const float* __restrict__ Hres_l,
    const float* __restrict__ Hpre_l,
    const float* __restrict__ Hpost_l,
    float* __restrict__ ws_small,
    int D4)
{
    const int t = threadIdx.x;
    const int wave = t >> 6;
    const int lane = t & 63;

    if (wave == 0) {
        float a = (lane < E * E) ? Hres_l[lane] : -1e30f;
        float m = a;
#pragma unroll
        for (int off = 1; off < 16; off <<= 1)
            m = fmaxf(m, __shfl_xor(m, off, 16));
        a = expf(a - m);
        for (int it = 0; it < SINKHORN_ITERS; ++it) {
            float rs = a;                       // row sum (lanes sharing r)
            rs += __shfl_xor(rs, 1, 4);
            rs += __shfl_xor(rs, 2, 4);
            a /= (rs + SINKHORN_EPS);
            float cs = a;                       // col sum (lanes sharing c)
            cs += __shfl_xor(cs, 4, 16);
            cs += __shfl_xor(cs, 8, 16);
            a /= (cs + SINKHORN_EPS);
        }
        if (lane < E * E) ws_small[lane] = a;
    }

    for (int pi = 0; pi < 2; ++pi) {
        const int p = wave * 2 + pi;            // 0..7: mat=p>>2, e=p&3
        const int mat = p >> 2, e = p & 3;
        const f4* rowp = (const f4*)((mat ? Hpost_l : Hpre_l) + (size_t)e * D4 * 4);
        float m = -1e30f;
        for (int i = lane; i < D4; i += 64) {
            f4 v = rowp[i];
            m = fmaxf(fmaxf(fmaxf(m, v.x), v.y), fmaxf(v.z, v.w));
        }
#pragma unroll
        for (int off = 1; off < 64; off <<= 1)
            m = fmaxf(m, __shfl_xor(m, off, 64));
        float s = 0.f;
        for (int i = lane; i < D4; i += 64) {
            f4 v = rowp[i];
            s += expf(v.x - m) + expf(v.y - m) + expf(v.z - m) + expf(v.w - m);
        }
#pragma unroll
        for (int off = 1; off < 64; off <<= 1)
            s += __shfl_xor(s, off, 64);
        if (lane == 0) { ws_small[16 + p] = m; ws_small[24 + p] = s; }
    }
}

// ---------------------------------------------------------------------------
// prep_write: D4/TPB blocks, one f4 column per thread.
// ws_pre = softmax(H_pre); ws_post2 = H_res @ softmax(H_post).
// ---------------------------------------------------------------------------
__global__ __launch_bounds__(TPB) void prep_write(
    const float* __restrict__ Hpre_l,
    const float* __restrict__ Hpost_l,
    const float* __restrict__ ws_small,
    f4* __restrict__ wpre4,
    f4* __restrict__ wpost4,
    int D4)
{
    const int i = blockIdx.x * TPB + threadIdx.x;
    if (i >= D4) return;

    float hres[E * E];
#pragma unroll
    for (int k = 0; k < E * E; ++k) hres[k] = ws_small[k];
    float mpre[E], spre[E], mpost[E], spost[E];
#pragma unroll
    for (int e = 0; e < E; ++e) {
        mpre[e]  = ws_small[16 + e];     spre[e]  = 1.f / ws_small[24 + e];
        mpost[e] = ws_small[16 + E + e]; spost[e] = 1.f / ws_small[24 + E + e];
    }

    const f4* pre_l4  = (const f4*)Hpre_l;
    const f4* post_l4 = (const f4*)Hpost_l;
    f4 postv[E];
#pragma unroll
    for (int e = 0; e < E; ++e) {
        f4 v = pre_l4[(size_t)e * D4 + i];
        f4 o;
        o.x = expf(v.x - mpre[e]) * spre[e];
        o.y = expf(v.y - mpre[e]) * spre[e];
        o.z = expf(v.z - mpre[e]) * spre[e];
        o.w = expf(v.w - mpre[e]) * spre[e];
        wpre4[(size_t)e * D4 + i] = o;
        f4 w = post_l4[(size_t)e * D4 + i];
        postv[e].x = expf(w.x - mpost[e]) * spost[e];
        postv[e].y = expf(w.y - mpost[e]) * spost[e];
        postv[e].z = expf(w.z - mpost[e]) * spost[e];
        postv[e].w = expf(w.w - mpost[e]) * spost[e];
    }
#pragma unroll
    for (int ep = 0; ep < E; ++ep) {
        f4 o = hres[ep * E + 0] * postv[0] + hres[ep * E + 1] * postv[1] +
               hres[ep * E + 2] * postv[2] + hres[ep * E + 3] * postv[3];
        wpost4[(size_t)ep * D4 + i] = o;
    }
}

// ---------------------------------------------------------------------------
// mhc_main (fused): 8 rows per 256-thread block.
//  Phase 1: part dot-products, compile-time-unrolled chunk loop (CT != 0)
//           -> deep load MLP; butterfly + LDS cross-wave reduce.
//  Phase 2: out[row][d] = sum_e xp[row][e] * ws_post2[e][d], plain stores.
// ---------------------------------------------------------------------------
template <int CT>
__global__ __launch_bounds__(TPB) void mhc_main(
    const f4* __restrict__ x4,
    const f4* __restrict__ pre4,
    const f4* __restrict__ post4,
    f4* __restrict__ out4,
    int D4, int chunks_rt)
{
    __shared__ float wred[NWAVES][RPB][E];
    const int t = threadIdx.x;
    const int wave = t >> 6;
    const long row0 = (long)blockIdx.x * RPB;
    const int chunks = CT ? CT : chunks_rt;

    float part[RPB][E];
#pragma unroll
    for (int r = 0; r < RPB; ++r)
#pragma unroll
        for (int e = 0; e < E; ++e) part[r][e] = 0.f;

#pragma unroll
    for (int k = 0; k < chunks; ++k) {
        const int d4 = k * TPB + t;
        f4 hp[E];
#pragma unroll
        for (int e = 0; e < E; ++e) hp[e] = pre4[(size_t)e * D4 + d4];
#pragma unroll
        for (int r = 0; r < RPB; ++r) {
            f4 xv = x4[(row0 + r) * D4 + d4];
#pragma unroll
            for (int e = 0; e < E; ++e)
                part[r][e] += xv.x * hp[e].x + xv.y * hp[e].y +
                              xv.z * hp[e].z + xv.w * hp[e].w;
        }
    }

#pragma unroll
    for (int r = 0; r < RPB; ++r)
#pragma unroll
        for (int e = 0; e < E; ++e) {
            float v = part[r][e];
#pragma unroll
            for (int off = 1; off < 64; off <<= 1) v += __shfl_xor(v, off, 64);
            if ((t & 63) == 0) wred[wave][r][e] = v;
        }
    __syncthreads();

    float xp[RPB][E];
#pragma unroll
    for (int r = 0; r < RPB; ++r)
#pragma unroll
        for (int e = 0; e < E; ++e) {
            float v = 0.f;
#pragma unroll
            for (int w = 0; w < NWAVES; ++w) v += wred[w][r][e];
            xp[r][e] = v;
        }

#pragma unroll
    for (int k = 0; k < chunks; ++k) {
        const int d4 = k * TPB + t;
        f4 hq[E];
#pragma unroll
        for (int e = 0; e < E; ++e) hq[e] = post4[(size_t)e * D4 + d4];
#pragma unroll
        for (int r = 0; r < RPB; ++r) {
            f4 o = xp[r][0] * hq[0] + xp[r][1] * hq[1] +
                   xp[r][2] * hq[2] + xp[r][3] * hq[3];
            out4[(row0 + r) * D4 + d4] = o;
        }
    }
}

extern "C" void kernel_launch(void* const* d_in, const int* in_sizes, int n_in,
                              void* d_out, int out_size, void* d_ws, size_t ws_size,
                              hipStream_t stream) {
    const float* x     = (const float*)d_in[0];
    const float* Hres  = (const float*)d_in[1];
    const float* Hpre  = (const float*)d_in[2];
    const float* Hpost = (const float*)d_in[3];
    float* out = (float*)d_out;

    const int D = in_sizes[2] / E;                  // 4096
    const long rows = (long)in_sizes[0] / D;        // B*S = 16384
    const int D4 = D / 4;
    const int chunks = D4 / TPB;                    // 4 for D=4096

    float* ws_pre   = (float*)d_ws;                 // E*D floats
    float* ws_post2 = ws_pre + (size_t)E * D;       // E*D floats
    float* ws_small = ws_post2 + (size_t)E * D;     // 32 floats

    prep_stats<<<1, TPB, 0, stream>>>(Hres, Hpre, Hpost, ws_small, D4);
    prep_write<<<(D4 + TPB - 1) / TPB, TPB, 0, stream>>>(
        Hpre, Hpost, ws_small, (f4*)ws_pre, (f4*)ws_post2, D4);

    const int grid = (int)(rows / RPB);             // 2048
    if (chunks == 4 && D4 % TPB == 0) {
        mhc_main<4><<<grid, TPB, 0, stream>>>((const f4*)x, (const f4*)ws_pre,
                                              (const f4*)ws_post2, (f4*)out,
                                              D4, chunks);
    } else {
        mhc_main<0><<<grid, TPB, 0, stream>>>((const f4*)x, (const f4*)ws_pre,
                                              (const f4*)ws_post2, (f4*)out,
                                              D4, chunks);
    }
}

// Round 5
// 122.191 us; speedup vs baseline: 1.1927x; 1.1927x over previous
//
#include <hip/hip_runtime.h>
#include <math.h>

#define E 4
#define TPB 256
#define RPB 8
#define NWAVES (TPB / 64)
#define SINKHORN_ITERS 20
#define SINKHORN_EPS 1e-6f

typedef float f4 __attribute__((ext_vector_type(4)));

// ws layout: [0, E*D)        ws_pre    = softmax(H_pre)            (E x D)
//            [E*D, 2*E*D)    ws_post2  = H_res @ softmax(H_post)   (E x D)
//            [2*E*D, +32)    ws_small: hres[16], mx[8], sm[8]
//            [2*E*D+32, ...) ws_xpre: rows*E floats

// ---------------------------------------------------------------------------
// prep_stats: 1 block, no barriers. Sinkhorn on wave 0 (lanes 0-15, shfl
// butterflies); each wave computes softmax stats (max,sumexp) for 2 of the 8
// (mat,row) pairs with f4 loads + 6-step butterfly.
// ---------------------------------------------------------------------------
__global__ __launch_bounds__(TPB) void prep_stats(
    const float* __restrict__ Hres_l,
    const float* __restrict__ Hpre_l,
    const float* __restrict__ Hpost_l,
    float* __restrict__ ws_small,
    int D4)
{
    const int t = threadIdx.x;
    const int wave = t >> 6;
    const int lane = t & 63;

    if (wave == 0) {
        float a = (lane < E * E) ? Hres_l[lane] : -1e30f;
        float m = a;
#pragma unroll
        for (int off = 1; off < 16; off <<= 1)
            m = fmaxf(m, __shfl_xor(m, off, 16));
        a = expf(a - m);
        for (int it = 0; it < SINKHORN_ITERS; ++it) {
            float rs = a;                       // row sum (lanes sharing r)
            rs += __shfl_xor(rs, 1, 4);
            rs += __shfl_xor(rs, 2, 4);
            a /= (rs + SINKHORN_EPS);
            float cs = a;                       // col sum (lanes sharing c)
            cs += __shfl_xor(cs, 4, 16);
            cs += __shfl_xor(cs, 8, 16);
            a /= (cs + SINKHORN_EPS);
        }
        if (lane < E * E) ws_small[lane] = a;
    }

    for (int pi = 0; pi < 2; ++pi) {
        const int p = wave * 2 + pi;            // 0..7: mat=p>>2, e=p&3
        const int mat = p >> 2, e = p & 3;
        const f4* rowp = (const f4*)((mat ? Hpost_l : Hpre_l) + (size_t)e * D4 * 4);
        float m = -1e30f;
        for (int i = lane; i < D4; i += 64) {
            f4 v = rowp[i];
            m = fmaxf(fmaxf(fmaxf(m, v.x), v.y), fmaxf(v.z, v.w));
        }
#pragma unroll
        for (int off = 1; off < 64; off <<= 1)
            m = fmaxf(m, __shfl_xor(m, off, 64));
        float s = 0.f;
        for (int i = lane; i < D4; i += 64) {
            f4 v = rowp[i];
            s += expf(v.x - m) + expf(v.y - m) + expf(v.z - m) + expf(v.w - m);
        }
#pragma unroll
        for (int off = 1; off < 64; off <<= 1)
            s += __shfl_xor(s, off, 64);
        if (lane == 0) { ws_small[16 + p] = m; ws_small[24 + p] = s; }
    }
}

// ---------------------------------------------------------------------------
// prep_write: D4/TPB blocks (=4), one f4 column per thread.
// ws_pre = softmax(H_pre); ws_post2 = H_res @ softmax(H_post).
// ---------------------------------------------------------------------------
__global__ __launch_bounds__(TPB) void prep_write(
    const float* __restrict__ Hpre_l,
    const float* __restrict__ Hpost_l,
    const float* __restrict__ ws_small,
    f4* __restrict__ wpre4,
    f4* __restrict__ wpost4,
    int D4)
{
    const int i = blockIdx.x * TPB + threadIdx.x;
    if (i >= D4) return;

    float hres[E * E];
#pragma unroll
    for (int k = 0; k < E * E; ++k) hres[k] = ws_small[k];
    float mpre[E], spre[E], mpost[E], spost[E];
#pragma unroll
    for (int e = 0; e < E; ++e) {
        mpre[e]  = ws_small[16 + e];     spre[e]  = 1.f / ws_small[24 + e];
        mpost[e] = ws_small[16 + E + e]; spost[e] = 1.f / ws_small[24 + E + e];
    }

    const f4* pre_l4  = (const f4*)Hpre_l;
    const f4* post_l4 = (const f4*)Hpost_l;
    f4 postv[E];
#pragma unroll
    for (int e = 0; e < E; ++e) {
        f4 v = pre_l4[(size_t)e * D4 + i];
        f4 o;
        o.x = expf(v.x - mpre[e]) * spre[e];
        o.y = expf(v.y - mpre[e]) * spre[e];
        o.z = expf(v.z - mpre[e]) * spre[e];
        o.w = expf(v.w - mpre[e]) * spre[e];
        wpre4[(size_t)e * D4 + i] = o;
        f4 w = post_l4[(size_t)e * D4 + i];
        postv[e].x = expf(w.x - mpost[e]) * spost[e];
        postv[e].y = expf(w.y - mpost[e]) * spost[e];
        postv[e].z = expf(w.z - mpost[e]) * spost[e];
        postv[e].w = expf(w.w - mpost[e]) * spost[e];
    }
#pragma unroll
    for (int ep = 0; ep < E; ++ep) {
        f4 o = hres[ep * E + 0] * postv[0] + hres[ep * E + 1] * postv[1] +
               hres[ep * E + 2] * postv[2] + hres[ep * E + 3] * postv[3];
        wpost4[(size_t)ep * D4 + i] = o;
    }
}

// ---------------------------------------------------------------------------
// xpre_kernel: x_pre[row][e] = dot(x[row], ws_pre[e]). Pure read stream of x
// (nontemporal). 8 rows per block. Reduction = value-halving butterfly
// (31 shfl instead of 192): step s keeps packed elements whose index-parity
// == lane-bit s; final value v = lane&31, then one xor-32 shfl.
// ---------------------------------------------------------------------------
__global__ __launch_bounds__(TPB) void xpre_kernel(
    const f4* __restrict__ x4,
    const f4* __restrict__ pre4,
    float* __restrict__ xpre,
    int D4, int chunks)
{
    __shared__ float wred[NWAVES][RPB * E];
    const int t = threadIdx.x;
    const int wave = t >> 6;
    const int lane = t & 63;
    const long row0 = (long)blockIdx.x * RPB;

    float val[RPB * E];                  // packed partials, idx = r*E+e
#pragma unroll
    for (int i = 0; i < RPB * E; ++i) val[i] = 0.f;

    for (int k = 0; k < chunks; ++k) {
        const int d4 = k * TPB + t;
        f4 hp[E];
#pragma unroll
        for (int e = 0; e < E; ++e) hp[e] = pre4[(size_t)e * D4 + d4];
#pragma unroll
        for (int r = 0; r < RPB; ++r) {
            f4 xv = __builtin_nontemporal_load(&x4[(row0 + r) * D4 + d4]);
#pragma unroll
            for (int e = 0; e < E; ++e)
                val[r * E + e] += xv.x * hp[e].x + xv.y * hp[e].y +
                                  xv.z * hp[e].z + xv.w * hp[e].w;
        }
    }

    // value-halving butterfly: 32 -> 16 -> 8 -> 4 -> 2 -> 1 values/thread
    {
        const bool h0 = lane & 1;
        float a16[16];
#pragma unroll
        for (int i = 0; i < 16; ++i) {
            float send = h0 ? val[2 * i] : val[2 * i + 1];
            float recv = __shfl_xor(send, 1, 64);
            a16[i] = (h0 ? val[2 * i + 1] : val[2 * i]) + recv;
        }
        const bool h1 = (lane >> 1) & 1;
        float a8[8];
#pragma unroll
        for (int i = 0; i < 8; ++i) {
            float send = h1 ? a16[2 * i] : a16[2 * i + 1];
            float recv = __shfl_xor(send, 2, 64);
            a8[i] = (h1 ? a16[2 * i + 1] : a16[2 * i]) + recv;
        }
        const bool h2 = (lane >> 2) & 1;
        float a4[4];
#pragma unroll
        for (int i = 0; i < 4; ++i) {
            float send = h2 ? a8[2 * i] : a8[2 * i + 1];
            float recv = __shfl_xor(send, 4, 64);
            a4[i] = (h2 ? a8[2 * i + 1] : a8[2 * i]) + recv;
        }
        const bool h3 = (lane >> 3) & 1;
        float a2[2];
#pragma unroll
        for (int i = 0; i < 2; ++i) {
            float send = h3 ? a4[2 * i] : a4[2 * i + 1];
            float recv = __shfl_xor(send, 8, 64);
            a2[i] = (h3 ? a4[2 * i + 1] : a4[2 * i]) + recv;
        }
        const bool h4 = (lane >> 4) & 1;
        float send = h4 ? a2[0] : a2[1];
        float recv = __shfl_xor(send, 16, 64);
        float a1 = (h4 ? a2[1] : a2[0]) + recv;
        a1 += __shfl_xor(a1, 32, 64);    // cross 32-lane halves
        if (lane < 32) wred[wave][lane] = a1;   // v = lane & 31
    }
    __syncthreads();

    if (t < RPB * E) {                   // t = v = r*E + e
        float s = wred[0][t] + wred[1][t] + wred[2][t] + wred[3][t];
        const int r = t >> 2, e = t & 3;
        xpre[(row0 + r) * E + e] = s;
    }
}

// ---------------------------------------------------------------------------
// out_kernel: out[row][d] = sum_e x_pre[row][e] * ws_post2[e][d].
// Pure write stream (nontemporal stores).
// ---------------------------------------------------------------------------
__global__ __launch_bounds__(TPB) void out_kernel(
    const float* __restrict__ xpre,
    const f4* __restrict__ post4,
    f4* __restrict__ out4,
    int D4, int chunks)
{
    __shared__ float sxp[RPB * E];
    const int t = threadIdx.x;
    const long row0 = (long)blockIdx.x * RPB;

    if (t < RPB * E) sxp[t] = xpre[row0 * E + t];
    __syncthreads();

    float xp[RPB][E];
#pragma unroll
    for (int r = 0; r < RPB; ++r)
#pragma unroll
        for (int e = 0; e < E; ++e) xp[r][e] = sxp[r * E + e];

    for (int k = 0; k < chunks; ++k) {
        const int d4 = k * TPB + t;
        f4 hq[E];
#pragma unroll
        for (int e = 0; e < E; ++e) hq[e] = post4[(size_t)e * D4 + d4];
#pragma unroll
        for (int r = 0; r < RPB; ++r) {
            f4 o = xp[r][0] * hq[0] + xp[r][1] * hq[1] +
                   xp[r][2] * hq[2] + xp[r][3] * hq[3];
            __builtin_nontemporal_store(o, &out4[(row0 + r) * D4 + d4]);
        }
    }
}

extern "C" void kernel_launch(void* const* d_in, const int* in_sizes, int n_in,
                              void* d_out, int out_size, void* d_ws, size_t ws_size,
                              hipStream_t stream) {
    const float* x     = (const float*)d_in[0];
    const float* Hres  = (const float*)d_in[1];
    const float* Hpre  = (const float*)d_in[2];
    const float* Hpost = (const float*)d_in[3];
    float* out = (float*)d_out;

    const int D = in_sizes[2] / E;                  // 4096
    const long rows = (long)in_sizes[0] / D;        // B*S = 16384
    const int D4 = D / 4;
    const int chunks = D4 / TPB;                    // 4 for D=4096

    float* ws_pre   = (float*)d_ws;                 // E*D floats
    float* ws_post2 = ws_pre + (size_t)E * D;       // E*D floats
    float* ws_small = ws_post2 + (size_t)E * D;     // 32 floats
    float* ws_xpre  = ws_small + 32;                // rows*E floats

    prep_stats<<<1, TPB, 0, stream>>>(Hres, Hpre, Hpost, ws_small, D4);
    prep_write<<<(D4 + TPB - 1) / TPB, TPB, 0, stream>>>(
        Hpre, Hpost, ws_small, (f4*)ws_pre, (f4*)ws_post2, D4);

    const int grid = (int)(rows / RPB);             // 2048
    xpre_kernel<<<grid, TPB, 0, stream>>>((const f4*)x, (const f4*)ws_pre,
                                          ws_xpre, D4, chunks);
    out_kernel<<<grid, TPB, 0, stream>>>(ws_xpre, (const f4*)ws_post2,
                                         (f4*)out, D4, chunks);
}

// Round 6
// 110.786 us; speedup vs baseline: 1.3155x; 1.1030x over previous
//
#include <hip/hip_runtime.h>
#include <math.h>

#define E 4
#define TPB 256
#define RPB 8
#define NWAVES (TPB / 64)
#define SINKHORN_ITERS 20
#define SINKHORN_EPS 1e-6f

typedef float f4 __attribute__((ext_vector_type(4)));

// ws layout: [0, E*D)        ws_pre    = softmax(H_pre)            (E x D)
//            [E*D, 2*E*D)    ws_post2  = H_res @ softmax(H_post)   (E x D)
//            [2*E*D, +32)    ws_small: hres[16], mx[8], sm[8]
//            [2*E*D+32, ...) ws_xpre: rows*E floats

// ---------------------------------------------------------------------------
// prep_stats: 9 blocks, all latency paths parallel.
//  blocks 0-7: softmax stats (max, sumexp) for (mat,row) pair p = blockIdx
//              (256 threads, 4 f4/thread/pass, butterfly + LDS combine)
//  block 8   : sinkhorn on wave 0 (lanes 0-15, shfl butterflies)
// ---------------------------------------------------------------------------
__global__ __launch_bounds__(TPB) void prep_stats(
    const float* __restrict__ Hres_l,
    const float* __restrict__ Hpre_l,
    const float* __restrict__ Hpost_l,
    float* __restrict__ ws_small,
    int D4)
{
    const int t = threadIdx.x;
    const int wave = t >> 6;
    const int lane = t & 63;

    if (blockIdx.x == 8) {
        if (wave == 0) {
            float a = (lane < E * E) ? Hres_l[lane] : -1e30f;
            float m = a;
#pragma unroll
            for (int off = 1; off < 16; off <<= 1)
                m = fmaxf(m, __shfl_xor(m, off, 16));
            a = expf(a - m);
            for (int it = 0; it < SINKHORN_ITERS; ++it) {
                float rs = a;                   // row sum (lanes sharing r)
                rs += __shfl_xor(rs, 1, 4);
                rs += __shfl_xor(rs, 2, 4);
                a /= (rs + SINKHORN_EPS);
                float cs = a;                   // col sum (lanes sharing c)
                cs += __shfl_xor(cs, 4, 16);
                cs += __shfl_xor(cs, 8, 16);
                a /= (cs + SINKHORN_EPS);
            }
            if (lane < E * E) ws_small[lane] = a;
        }
        return;
    }

    __shared__ float redm[NWAVES], reds[NWAVES];
    const int p = blockIdx.x;                   // 0..7: mat=p>>2, e=p&3
    const int mat = p >> 2, e = p & 3;
    const f4* rowp = (const f4*)((mat ? Hpost_l : Hpre_l) + (size_t)e * D4 * 4);

    // pass 1: row max
    float m = -1e30f;
    for (int i = t; i < D4; i += TPB) {
        f4 v = rowp[i];
        m = fmaxf(fmaxf(fmaxf(m, v.x), v.y), fmaxf(v.z, v.w));
    }
#pragma unroll
    for (int off = 1; off < 64; off <<= 1)
        m = fmaxf(m, __shfl_xor(m, off, 64));
    if (lane == 0) redm[wave] = m;
    __syncthreads();
    m = fmaxf(fmaxf(redm[0], redm[1]), fmaxf(redm[2], redm[3]));

    // pass 2: sum of exp (L2-hot)
    float s = 0.f;
    for (int i = t; i < D4; i += TPB) {
        f4 v = rowp[i];
        s += expf(v.x - m) + expf(v.y - m) + expf(v.z - m) + expf(v.w - m);
    }
#pragma unroll
    for (int off = 1; off < 64; off <<= 1)
        s += __shfl_xor(s, off, 64);
    if (lane == 0) reds[wave] = s;
    __syncthreads();
    if (t == 0) {
        ws_small[16 + p] = m;
        ws_small[24 + p] = reds[0] + reds[1] + reds[2] + reds[3];
    }
}

// ---------------------------------------------------------------------------
// prep_write: D4/TPB blocks (=4), one f4 column per thread.
// ws_pre = softmax(H_pre); ws_post2 = H_res @ softmax(H_post).
// ---------------------------------------------------------------------------
__global__ __launch_bounds__(TPB) void prep_write(
    const float* __restrict__ Hpre_l,
    const float* __restrict__ Hpost_l,
    const float* __restrict__ ws_small,
    f4* __restrict__ wpre4,
    f4* __restrict__ wpost4,
    int D4)
{
    const int i = blockIdx.x * TPB + threadIdx.x;
    if (i >= D4) return;

    float hres[E * E];
#pragma unroll
    for (int k = 0; k < E * E; ++k) hres[k] = ws_small[k];
    float mpre[E], spre[E], mpost[E], spost[E];
#pragma unroll
    for (int e = 0; e < E; ++e) {
        mpre[e]  = ws_small[16 + e];     spre[e]  = 1.f / ws_small[24 + e];
        mpost[e] = ws_small[16 + E + e]; spost[e] = 1.f / ws_small[24 + E + e];
    }

    const f4* pre_l4  = (const f4*)Hpre_l;
    const f4* post_l4 = (const f4*)Hpost_l;
    f4 postv[E];
#pragma unroll
    for (int e = 0; e < E; ++e) {
        f4 v = pre_l4[(size_t)e * D4 + i];
        f4 o;
        o.x = expf(v.x - mpre[e]) * spre[e];
        o.y = expf(v.y - mpre[e]) * spre[e];
        o.z = expf(v.z - mpre[e]) * spre[e];
        o.w = expf(v.w - mpre[e]) * spre[e];
        wpre4[(size_t)e * D4 + i] = o;
        f4 w = post_l4[(size_t)e * D4 + i];
        postv[e].x = expf(w.x - mpost[e]) * spost[e];
        postv[e].y = expf(w.y - mpost[e]) * spost[e];
        postv[e].z = expf(w.z - mpost[e]) * spost[e];
        postv[e].w = expf(w.w - mpost[e]) * spost[e];
    }
#pragma unroll
    for (int ep = 0; ep < E; ++ep) {
        f4 o = hres[ep * E + 0] * postv[0] + hres[ep * E + 1] * postv[1] +
               hres[ep * E + 2] * postv[2] + hres[ep * E + 3] * postv[3];
        wpost4[(size_t)ep * D4 + i] = o;
    }
}

// ---------------------------------------------------------------------------
// xpre_kernel: x_pre[row][e] = dot(x[row], ws_pre[e]). Pure read stream of x
// (nontemporal). 8 rows per block. Reduction = value-halving butterfly
// (31 shfl instead of 192): step s keeps packed elements whose index-parity
// == lane-bit s; final value v = lane&31, then one xor-32 shfl.
// ---------------------------------------------------------------------------
__global__ __launch_bounds__(TPB) void xpre_kernel(
    const f4* __restrict__ x4,
    const f4* __restrict__ pre4,
    float* __restrict__ xpre,
    int D4, int chunks)
{
    __shared__ float wred[NWAVES][RPB * E];
    const int t = threadIdx.x;
    const int wave = t >> 6;
    const int lane = t & 63;
    const long row0 = (long)blockIdx.x * RPB;

    float val[RPB * E];                  // packed partials, idx = r*E+e
#pragma unroll
    for (int i = 0; i < RPB * E; ++i) val[i] = 0.f;

    for (int k = 0; k < chunks; ++k) {
        const int d4 = k * TPB + t;
        f4 hp[E];
#pragma unroll
        for (int e = 0; e < E; ++e) hp[e] = pre4[(size_t)e * D4 + d4];
#pragma unroll
        for (int r = 0; r < RPB; ++r) {
            f4 xv = __builtin_nontemporal_load(&x4[(row0 + r) * D4 + d4]);
#pragma unroll
            for (int e = 0; e < E; ++e)
                val[r * E + e] += xv.x * hp[e].x + xv.y * hp[e].y +
                                  xv.z * hp[e].z + xv.w * hp[e].w;
        }
    }

    // value-halving butterfly: 32 -> 16 -> 8 -> 4 -> 2 -> 1 values/thread
    {
        const bool h0 = lane & 1;
        float a16[16];
#pragma unroll
        for (int i = 0; i < 16; ++i) {
            float send = h0 ? val[2 * i] : val[2 * i + 1];
            float recv = __shfl_xor(send, 1, 64);
            a16[i] = (h0 ? val[2 * i + 1] : val[2 * i]) + recv;
        }
        const bool h1 = (lane >> 1) & 1;
        float a8[8];
#pragma unroll
        for (int i = 0; i < 8; ++i) {
            float send = h1 ? a16[2 * i] : a16[2 * i + 1];
            float recv = __shfl_xor(send, 2, 64);
            a8[i] = (h1 ? a16[2 * i + 1] : a16[2 * i]) + recv;
        }
        const bool h2 = (lane >> 2) & 1;
        float a4[4];
#pragma unroll
        for (int i = 0; i < 4; ++i) {
            float send = h2 ? a8[2 * i] : a8[2 * i + 1];
            float recv = __shfl_xor(send, 4, 64);
            a4[i] = (h2 ? a8[2 * i + 1] : a8[2 * i]) + recv;
        }
        const bool h3 = (lane >> 3) & 1;
        float a2[2];
#pragma unroll
        for (int i = 0; i < 2; ++i) {
            float send = h3 ? a4[2 * i] : a4[2 * i + 1];
            float recv = __shfl_xor(send, 8, 64);
            a2[i] = (h3 ? a4[2 * i + 1] : a4[2 * i]) + recv;
        }
        const bool h4 = (lane >> 4) & 1;
        float send = h4 ? a2[0] : a2[1];
        float recv = __shfl_xor(send, 16, 64);
        float a1 = (h4 ? a2[1] : a2[0]) + recv;
        a1 += __shfl_xor(a1, 32, 64);    // cross 32-lane halves
        if (lane < 32) wred[wave][lane] = a1;   // v = lane & 31
    }
    __syncthreads();

    if (t < RPB * E) {                   // t = v = r*E + e
        float s = wred[0][t] + wred[1][t] + wred[2][t] + wred[3][t];
        const int r = t >> 2, e = t & 3;
        xpre[(row0 + r) * E + e] = s;
    }
}

// ---------------------------------------------------------------------------
// out_kernel: out[row][d] = sum_e x_pre[row][e] * ws_post2[e][d].
// Pure write stream (nontemporal stores).
// ---------------------------------------------------------------------------
__global__ __launch_bounds__(TPB) void out_kernel(
    const float* __restrict__ xpre,
    const f4* __restrict__ post4,
    f4* __restrict__ out4,
    int D4, int chunks)
{
    __shared__ float sxp[RPB * E];
    const int t = threadIdx.x;
    const long row0 = (long)blockIdx.x * RPB;

    if (t < RPB * E) sxp[t] = xpre[row0 * E + t];
    __syncthreads();

    float xp[RPB][E];
#pragma unroll
    for (int r = 0; r < RPB; ++r)
#pragma unroll
        for (int e = 0; e < E; ++e) xp[r][e] = sxp[r * E + e];

    for (int k = 0; k < chunks; ++k) {
        const int d4 = k * TPB + t;
        f4 hq[E];
#pragma unroll
        for (int e = 0; e < E; ++e) hq[e] = post4[(size_t)e * D4 + d4];
#pragma unroll
        for (int r = 0; r < RPB; ++r) {
            f4 o = xp[r][0] * hq[0] + xp[r][1] * hq[1] +
                   xp[r][2] * hq[2] + xp[r][3] * hq[3];
            __builtin_nontemporal_store(o, &out4[(row0 + r) * D4 + d4]);
        }
    }
}

extern "C" void kernel_launch(void* const* d_in, const int* in_sizes, int n_in,
                              void* d_out, int out_size, void* d_ws, size_t ws_size,
                              hipStream_t stream) {
    const float* x     = (const float*)d_in[0];
    const float* Hres  = (const float*)d_in[1];
    const float* Hpre  = (const float*)d_in[2];
    const float* Hpost = (const float*)d_in[3];
    float* out = (float*)d_out;

    const int D = in_sizes[2] / E;                  // 4096
    const long rows = (long)in_sizes[0] / D;        // B*S = 16384
    const int D4 = D / 4;
    const int chunks = D4 / TPB;                    // 4 for D=4096

    float* ws_pre   = (float*)d_ws;                 // E*D floats
    float* ws_post2 = ws_pre + (size_t)E * D;       // E*D floats
    float* ws_small = ws_post2 + (size_t)E * D;     // 32 floats
    float* ws_xpre  = ws_small + 32;                // rows*E floats

    prep_stats<<<9, TPB, 0, stream>>>(Hres, Hpre, Hpost, ws_small, D4);
    prep_write<<<(D4 + TPB - 1) / TPB, TPB, 0, stream>>>(
        Hpre, Hpost, ws_small, (f4*)ws_pre, (f4*)ws_post2, D4);

    const int grid = (int)(rows / RPB);             // 2048
    xpre_kernel<<<grid, TPB, 0, stream>>>((const f4*)x, (const f4*)ws_pre,
                                          ws_xpre, D4, chunks);
    out_kernel<<<grid, TPB, 0, stream>>>(ws_xpre, (const f4*)ws_post2,
                                         (f4*)out, D4, chunks);
}